// Round 1
// baseline (129.465 us; speedup 1.0000x reference)
//
#include <hip/hip_runtime.h>
#include <hip/hip_bf16.h>

// Algebraic collapse: output depends only on tree level 4 (global patch mean).
// root[b,d] = (1/256 * sum_{h,w} patches[b,h,w,:]) . W_emb[d,:] + b_emb[d] + pos4[d]
// logits[b,k] = root[b,:] . W_cls[k,:] + b_cls[k]
// patch feature f = c*256 + pi*16 + pj maps to x[b, c, 16h+pi, 16w+pj].

// Kernel 1: partial patch-position sums.
// grid = (192, 2): blockIdx.x = b*3+c plane, blockIdx.y = row-half (h in [0,8) or [8,16)).
// block = 256 threads: t = pi*16 + s. Thread reads float4s at positions s, s+16, s+32, s+48
// in each of its 8 rows (rows 16h+pi). Each float4 covers pj quad (4s mod 16)..+3, which is
// invariant across its loads. shfl_xor(4),(8) reduces the 4 lanes sharing a pj quad.
__global__ void k_patch_sum(const float* __restrict__ x, float* __restrict__ mpart) {
    const int bc   = blockIdx.x;      // 0..191 = b*3 + c
    const int half = blockIdx.y;      // 0..1
    const float* plane = x + (size_t)bc * 65536;  // 256*256
    const int t  = threadIdx.x;
    const int pi = t >> 4;            // 0..15 across the 4 waves
    const int s  = t & 15;

    float4 acc = make_float4(0.f, 0.f, 0.f, 0.f);
    #pragma unroll
    for (int hh = 0; hh < 8; ++hh) {
        const int h = half * 8 + hh;
        const float4* row = (const float4*)(plane + (size_t)(h * 16 + pi) * 256);
        #pragma unroll
        for (int j = 0; j < 4; ++j) {
            float4 v = row[s + 16 * j];
            acc.x += v.x; acc.y += v.y; acc.z += v.z; acc.w += v.w;
        }
    }
    // Reduce across lanes s, s^4, s^8, s^12 (same pj quad, same pi — masks stay in-wave).
    acc.x += __shfl_xor(acc.x, 4); acc.y += __shfl_xor(acc.y, 4);
    acc.z += __shfl_xor(acc.z, 4); acc.w += __shfl_xor(acc.w, 4);
    acc.x += __shfl_xor(acc.x, 8); acc.y += __shfl_xor(acc.y, 8);
    acc.z += __shfl_xor(acc.z, 8); acc.w += __shfl_xor(acc.w, 8);

    if (s < 4) {
        const int b = bc / 3, c = bc % 3;
        // slab layout: mpart[half][b][768]
        float* dst = mpart + (size_t)half * 64 * 768 + (size_t)b * 768 + c * 256 + pi * 16 + s * 4;
        *(float4*)dst = acc;
    }
}

// Kernel 2: per-batch head. grid = 64, block = 256.
__global__ void k_head(const float* __restrict__ mpart,
                       const float* __restrict__ W_emb,
                       const float* __restrict__ b_emb,
                       const float* __restrict__ pos4,
                       const float* __restrict__ W_cls,
                       const float* __restrict__ b_cls,
                       float* __restrict__ out) {
    __shared__ float sm[768];
    __shared__ float sroot[128];
    const int b = blockIdx.x;
    const int t = threadIdx.x;

    // combine the two partial slabs, scale by 1/256 (the global patch mean)
    for (int f = t; f < 768; f += 256) {
        sm[f] = (mpart[(size_t)b * 768 + f] + mpart[(size_t)64 * 768 + (size_t)b * 768 + f])
                * (1.0f / 256.0f);
    }
    __syncthreads();

    if (t < 128) {
        const float4* wr = (const float4*)(W_emb + (size_t)t * 768);
        const float4* smv = (const float4*)sm;
        float acc = 0.f;
        #pragma unroll 4
        for (int f = 0; f < 192; ++f) {  // 192 float4 = 768 floats
            float4 w = wr[f];
            float4 m = smv[f];
            acc += w.x * m.x + w.y * m.y + w.z * m.z + w.w * m.w;
        }
        sroot[t] = acc + b_emb[t] + pos4[t];
    }
    __syncthreads();

    const float4* rv = (const float4*)sroot;
    for (int k = t; k < 1000; k += 256) {
        const float4* wc = (const float4*)(W_cls + (size_t)k * 128);
        float acc = 0.f;
        #pragma unroll 8
        for (int d = 0; d < 32; ++d) {  // 32 float4 = 128 floats
            float4 w = wc[d];
            float4 r = rv[d];
            acc += w.x * r.x + w.y * r.y + w.z * r.z + w.w * r.w;
        }
        out[(size_t)b * 1000 + k] = acc + b_cls[k];
    }
}

extern "C" void kernel_launch(void* const* d_in, const int* in_sizes, int n_in,
                              void* d_out, int out_size, void* d_ws, size_t ws_size,
                              hipStream_t stream) {
    const float* x     = (const float*)d_in[0];
    const float* W_emb = (const float*)d_in[1];
    const float* b_emb = (const float*)d_in[2];
    const float* pos4  = (const float*)d_in[7];
    const float* W_cls = (const float*)d_in[8];
    const float* b_cls = (const float*)d_in[9];
    float* out = (float*)d_out;

    float* mpart = (float*)d_ws;  // 2 * 64 * 768 floats = 393216 bytes

    dim3 grid1(192, 2);
    k_patch_sum<<<grid1, 256, 0, stream>>>(x, mpart);
    k_head<<<64, 256, 0, stream>>>(mpart, W_emb, b_emb, pos4, W_cls, b_cls, out);
}